// Round 7
// baseline (2704.690 us; speedup 1.0000x reference)
//
#include <hip/hip_runtime.h>
#include <cstdint>
#include <cstddef>

// Problem constants (from reference: B=4, C=64, H=288, W=432, TEM=6)
#define NB 4
#define NC 64
#define HH 288
#define WW 432
#define PW 72                      // W / TEM
#define NV (HH*WW)                 // 124416 vertices
#define R_PER ((HH-1)*PW)          // 20664 row (vertical) edges per phase
#define C_PER (HH*(PW-1))          // 20448 col (horizontal) edges per phase
#define X_PER (HH*PW)              // 20736 cross edges per phase pair
#define PAIRW (R_PER + C_PER)      // 41112 weight-layout per-phase block
#define ROWS_TOT (6*R_PER)         // 123984
#define ROWCOL (6*PAIRW)           // 246672
#define NE (ROWCOL + 5*X_PER)      // 350352 edges
#define NEB ((NE + 255)/256)       // 1369 blocks per batch for edge kernels
#define NTREE (NV-1)               // 124415
#define CHUNK 4096
#define NCHUNK ((NE + CHUNK - 1)/CHUNK)   // 86

typedef unsigned long long ull;

// ---- edge id -> endpoints, per the INDEX layout (rows ++ cols ++ cross) ----
__device__ __forceinline__ void index_uv(int e, int& u, int& v) {
    if (e < ROWS_TOT) {
        int t = e / R_PER, l = e - t * R_PER;
        int h = l / PW, x = l - h * PW;
        u = h * WW + t * PW + x; v = u + WW;
    } else if (e < ROWCOL) {
        int q = e - ROWS_TOT;
        int t = q / C_PER, l = q - t * C_PER;
        int h = l / (PW-1), x = l - h * (PW-1);
        u = h * WW + t * PW + x; v = u + 1;
    } else {
        int q = e - ROWCOL;
        int t = q / X_PER, l = q - t * X_PER;
        int h = l / PW, x = l - h * PW;
        u = h * WW + t * PW + x; v = u + PW;
    }
}

// root under parent forest; handles unbroken 2-cycles (mutual min edge) by
// rooting the smaller id — exactly the reference's (gp==idx)&(idx<parent) rule.
__device__ __forceinline__ int rootOf(const int* __restrict__ par, int c) {
    while (true) {
        int p = par[c];
        if (p == c) return c;
        int pp = par[p];
        if (pp == c) return c < p ? c : p;
        c = p;
    }
}

__global__ __launch_bounds__(256) void init_kernel(int* comp, int* parent,
                                                   ull* minkey, unsigned char* mask,
                                                   int* cnt) {
    int i = blockIdx.x * 256 + threadIdx.x;
    int b = blockIdx.y;
    if (i < NV) {
        comp[(size_t)b*NV + i] = i;
        parent[(size_t)b*NV + i] = i;
        minkey[(size_t)b*NV + i] = ~0ULL;
    }
    if (i < NE) mask[(size_t)b*NE + i] = 0;
    if (b == 0 && i < NB) cnt[i] = 0;
}

// Stencil key kernel fused with Borůvka round 0 (~25 us, HBM-bound).
// Thread = vertex (h,x). Computes the 3 incident forward diffs (vertical,
// horizontal, cross) in one pass over channels, writes keys (weight slot ==
// edge id), and — since round-0 components are singletons — atomicMins the
// key straight into minkey[u], minkey[v] using the INDEX-layout endpoints.
__global__ __launch_bounds__(256) void key0_kernel(const float* __restrict__ fm,
                                                   ull* __restrict__ keys,
                                                   ull* __restrict__ minkey) {
    int i = blockIdx.x * 256 + threadIdx.x;
    int b = blockIdx.y;
    if (i >= NV) return;
    int h = i / WW, x = i - h * WW;
    int t = x / PW, xr = x - t * PW;
    bool hv = (h < HH-1);
    bool hh = (xr < PW-1);
    bool hx = (x < WW-PW);
    int ov = hv ? WW : 0;          // invalid -> reload self, diff = 0
    int oh = hh ? 1  : 0;
    int ox = hx ? PW : 0;
    const float* base = fm + (size_t)b * NC * NV + i;
    float sv = 0.f, sh_ = 0.f, sx = 0.f;
    #pragma unroll 8
    for (int ch = 0; ch < NC; ++ch) {
        const float* p = base + (size_t)ch * NV;
        float f0 = p[0];
        float dv = f0 - p[ov];
        float dh = f0 - p[oh];
        float dx = f0 - p[ox];
        sv += dv * dv; sh_ += dh * dh; sx += dx * dx;
    }
    ull* mk = minkey + (size_t)b * NV;
    ull* ky = keys + (size_t)b * NE;
    if (hv) {
        int e = t * PAIRW + h * PW + xr;
        ull k = ((ull)__float_as_uint(sv) << 32) | (unsigned int)e;
        ky[e] = k;
        int u, v; index_uv(e, u, v);
        atomicMin(&mk[u], k); atomicMin(&mk[v], k);
    }
    if (hh) {
        int e = t * PAIRW + R_PER + h * (PW-1) + xr;
        ull k = ((ull)__float_as_uint(sh_) << 32) | (unsigned int)e;
        ky[e] = k;
        int u, v; index_uv(e, u, v);
        atomicMin(&mk[u], k); atomicMin(&mk[v], k);
    }
    if (hx) {
        int e = ROWCOL + t * X_PER + h * PW + xr;
        ull k = ((ull)__float_as_uint(sx) << 32) | (unsigned int)e;
        ky[e] = k;
        int u, v; index_uv(e, u, v);
        atomicMin(&mk[u], k); atomicMin(&mk[v], k);
    }
}

// Global Borůvka scan (rounds 1..K-1): coalesced over all edges.
__global__ __launch_bounds__(256) void scan_kernel(const ull* __restrict__ keys,
                                                   int* __restrict__ comp,
                                                   const int* __restrict__ parent,
                                                   ull* __restrict__ minkey) {
    int e = blockIdx.x * 256 + threadIdx.x;
    int b = blockIdx.y;
    if (e >= NE) return;
    const int* par = parent + (size_t)b * NV;
    int* cmp = comp + (size_t)b * NV;
    int u, v; index_uv(e, u, v);
    int cu = rootOf(par, cmp[u]); if (cmp[u] != cu) cmp[u] = cu;  // benign race
    int cv = rootOf(par, cmp[v]); if (cmp[v] != cv) cmp[v] = cv;
    if (cu != cv) {
        ull k = keys[(size_t)b * NE + e];
        ull* mk = minkey + (size_t)b * NV;
        if (k < mk[cu]) atomicMin(&mk[cu], k);   // pre-check kills hot-slot serialization
        if (k < mk[cv]) atomicMin(&mk[cv], k);
    }
}

// Round-K scan: same, plus wave-aggregated append of surviving edges to a
// compact list for the finalize kernel.
__global__ __launch_bounds__(256) void scan_append_kernel(const ull* __restrict__ keys,
                                                          int* __restrict__ comp,
                                                          const int* __restrict__ parent,
                                                          ull* __restrict__ minkey,
                                                          int* __restrict__ list,
                                                          int* __restrict__ cnt) {
    int e = blockIdx.x * 256 + threadIdx.x;
    int b = blockIdx.y;
    bool live = false;
    int cu = 0, cv = 0;
    if (e < NE) {
        const int* par = parent + (size_t)b * NV;
        int* cmp = comp + (size_t)b * NV;
        int u, v; index_uv(e, u, v);
        cu = rootOf(par, cmp[u]); if (cmp[u] != cu) cmp[u] = cu;
        cv = rootOf(par, cmp[v]); if (cmp[v] != cv) cmp[v] = cv;
        live = (cu != cv);
    }
    if (live) {
        ull k = keys[(size_t)b * NE + e];
        ull* mk = minkey + (size_t)b * NV;
        if (k < mk[cu]) atomicMin(&mk[cu], k);
        if (k < mk[cv]) atomicMin(&mk[cv], k);
    }
    ull m = __ballot(live ? 1 : 0);
    if (m) {
        int lane = threadIdx.x & 63;
        int leader = __ffsll((long long)m) - 1;
        int base = 0;
        if (lane == leader) base = atomicAdd(&cnt[b], __popcll(m));
        base = __shfl(base, leader);
        if (live) list[(size_t)b * NE + base + __popcll(m & ((1ull << lane) - 1))] = e;
    }
}

// Per component: read winning edge, mark mask, hook parent, reset minkey.
__global__ __launch_bounds__(256) void select_kernel(const int* __restrict__ comp,
                                                     int* __restrict__ parent,
                                                     ull* __restrict__ minkey,
                                                     unsigned char* __restrict__ mask) {
    int c = blockIdx.x * 256 + threadIdx.x;
    int b = blockIdx.y;
    if (c >= NV) return;
    size_t off = (size_t)b * NV;
    ull k = minkey[off + c];
    int par = c;
    if (k != ~0ULL) {
        minkey[off + c] = ~0ULL;                 // reset only touched slots
        int e = (int)(k & 0xffffffffu);
        mask[(size_t)b * NE + e] = 1;            // idempotent
        int u, v; index_uv(e, u, v);
        int cu = comp[off + u], cv = comp[off + v];
        par = (cu == c) ? cv : cu;               // "other" component
    }
    if (parent[off + c] != par) parent[off + c] = par;
}

// Remaining Borůvka rounds in ONE kernel: 1 block (1024 threads) per batch,
// intra-block __syncthreads() replaces ~28 kernel launches. Scan phase builds
// a compacted (e,cu,cv,k) list + atomicMin minkey; select phase is edge-side:
// edge e is component c's winner iff minkey[c]==key(e) (keys unique), so no
// NV sweep and no root list. Loops until no cross-component edges remain —
// MST is unique under the strict (bits(w),id) order, so fewer rounds than the
// reference's 18 is still exact.
__global__ __launch_bounds__(1024) void finalize_kernel(const ull* __restrict__ keys,
                                                        int* __restrict__ comp,
                                                        int* __restrict__ parent,
                                                        ull* __restrict__ minkey,
                                                        unsigned char* __restrict__ mask,
                                                        int* __restrict__ eL0,
                                                        int* __restrict__ eL1,
                                                        int* __restrict__ cuL,
                                                        int* __restrict__ cvL,
                                                        ull* __restrict__ kL,
                                                        const int* __restrict__ cnt) {
    const int b = blockIdx.x;
    const int tid = threadIdx.x;
    const ull* ky = keys + (size_t)b * NE;
    int* cmp = comp + (size_t)b * NV;
    int* par = parent + (size_t)b * NV;
    ull* mk  = minkey + (size_t)b * NV;
    unsigned char* msk = mask + (size_t)b * NE;
    int* listA = eL0 + (size_t)b * NE;
    int* listB = eL1 + (size_t)b * NE;
    int* cu_ = cuL + (size_t)b * NE;
    int* cv_ = cvL + (size_t)b * NE;
    ull* k_  = kL  + (size_t)b * NE;
    __shared__ int s_cnt;

    int nE = cnt[b];
    int cur = 0;
    while (nE > 0) {
        if (tid == 0) s_cnt = 0;
        __syncthreads();
        int* src = cur ? listB : listA;
        int* dst = cur ? listA : listB;
        // ---- scan: recompute roots, filter, fill minkey, compact ----
        for (int base = 0; base < nE; base += 1024) {
            int i = base + tid;
            bool live = false; int e = 0, cu = 0, cv = 0; ull k = 0;
            if (i < nE) {
                e = src[i];
                int u, v; index_uv(e, u, v);
                cu = rootOf(par, cmp[u]); if (cmp[u] != cu) cmp[u] = cu;
                cv = rootOf(par, cmp[v]); if (cmp[v] != cv) cmp[v] = cv;
                live = (cu != cv);
                if (live) {
                    k = ky[e];
                    atomicMin(&mk[cu], k);
                    atomicMin(&mk[cv], k);
                }
            }
            ull m = __ballot(live ? 1 : 0);
            if (m) {
                int lane = tid & 63;
                int leader = __ffsll((long long)m) - 1;
                int wb = 0;
                if (lane == leader) wb = atomicAdd(&s_cnt, __popcll(m));
                wb = __shfl(wb, leader);
                if (live) {
                    int pos = wb + __popcll(m & ((1ull << lane) - 1));
                    dst[pos] = e; cu_[pos] = cu; cv_[pos] = cv; k_[pos] = k;
                }
            }
        }
        __syncthreads();                  // drains vmcnt: minkey/list visible
        int n2 = s_cnt;
        if (n2 == 0) break;               // no survivors: minkey untouched, done
        // ---- select (edge-side): unique winner per component hooks+marks ----
        for (int i = tid; i < n2; i += 1024) {
            int e = dst[i], cu = cu_[i], cv = cv_[i];
            ull k = k_[i];
            if (mk[cu] == k) { msk[e] = 1; par[cu] = cv; mk[cu] = ~0ULL; }
            if (mk[cv] == k) { msk[e] = 1; par[cv] = cu; mk[cv] = ~0ULL; }
        }
        __syncthreads();                  // hooks visible before next scan
        nE = n2; cur ^= 1;
    }
}

__global__ __launch_bounds__(256) void count_kernel(const unsigned char* __restrict__ mask,
                                                    int* __restrict__ counts) {
    int b = blockIdx.y, ck = blockIdx.x, t = threadIdx.x;
    const unsigned char* m = mask + (size_t)b * NE;
    int base_e = ck * CHUNK + t * 16;
    int cnt = 0;
    #pragma unroll
    for (int i = 0; i < 16; ++i) {
        int e = base_e + i;
        if (e < NE && m[e]) cnt++;
    }
    __shared__ int sh[256];
    sh[t] = cnt;
    __syncthreads();
    for (int o = 128; o > 0; o >>= 1) {
        if (t < o) sh[t] += sh[t + o];
        __syncthreads();
    }
    if (t == 0) counts[b * NCHUNK + ck] = sh[0];
}

// Write with inline offset computation (reduce over counts[0..ck-1]).
__global__ __launch_bounds__(256) void write_kernel(const unsigned char* __restrict__ mask,
                                                    const int* __restrict__ counts,
                                                    int* __restrict__ out) {
    int b = blockIdx.y, ck = blockIdx.x, t = threadIdx.x;
    __shared__ int sh[256];
    __shared__ int shOff[128];
    shOff[t & 127] = 0;
    __syncthreads();
    if (t < NCHUNK && t < ck) shOff[t] = counts[b * NCHUNK + t];
    __syncthreads();
    for (int o = 64; o > 0; o >>= 1) {
        if (t < o) shOff[t] += shOff[t + o];
        __syncthreads();
    }
    int blockOff = shOff[0];

    const unsigned char* m = mask + (size_t)b * NE;
    int base_e = ck * CHUNK + t * 16;
    int cnt = 0;
    #pragma unroll
    for (int i = 0; i < 16; ++i) {
        int e = base_e + i;
        if (e < NE && m[e]) cnt++;
    }
    sh[t] = cnt;
    __syncthreads();
    for (int o = 1; o < 256; o <<= 1) {          // Hillis-Steele inclusive scan
        int v = 0;
        if (t >= o) v = sh[t - o];
        __syncthreads();
        sh[t] += v;
        __syncthreads();
    }
    int pos = blockOff + (sh[t] - cnt);
    for (int i = 0; i < 16; ++i) {
        int e = base_e + i;
        if (e < NE && m[e]) {
            if (pos < NTREE) out[(size_t)b * NTREE + pos] = e;
            pos++;
        }
    }
}

extern "C" void kernel_launch(void* const* d_in, const int* in_sizes, int n_in,
                              void* d_out, int out_size, void* d_ws, size_t ws_size,
                              hipStream_t stream) {
    const float* fm = (const float*)d_in[0];
    int* out = (int*)d_out;   // reference output dtype is int32

    char* ws = (char*)d_ws;
    size_t off = 0;
    auto alloc = [&](size_t bytes) -> void* {
        void* p = ws + off;
        off += (bytes + 255) & ~(size_t)255;
        return p;
    };
    ull* keys    = (ull*)alloc((size_t)NB * NE * 8);
    ull* minkey  = (ull*)alloc((size_t)NB * NV * 8);
    int* comp    = (int*)alloc((size_t)NB * NV * 4);
    int* parent  = (int*)alloc((size_t)NB * NV * 4);
    unsigned char* mask = (unsigned char*)alloc((size_t)NB * NE);
    int* counts  = (int*)alloc((size_t)NB * NCHUNK * 4);
    int* eL0     = (int*)alloc((size_t)NB * NE * 4);
    int* eL1     = (int*)alloc((size_t)NB * NE * 4);
    int* cuL     = (int*)alloc((size_t)NB * NE * 4);
    int* cvL     = (int*)alloc((size_t)NB * NE * 4);
    ull* kL      = (ull*)alloc((size_t)NB * NE * 8);
    int* cnt     = (int*)alloc(NB * 4);

    dim3 blk(256);
    dim3 gE(NEB, NB);
    dim3 gV((NV + 255) / 256, NB);

    init_kernel<<<gE, blk, 0, stream>>>(comp, parent, minkey, mask, cnt);
    key0_kernel<<<gV, blk, 0, stream>>>(fm, keys, minkey);         // round 0 scan fused
    select_kernel<<<gV, blk, 0, stream>>>(comp, parent, minkey, mask);   // round 0
    // rounds 1..2 global
    scan_kernel<<<gE, blk, 0, stream>>>(keys, comp, parent, minkey);
    select_kernel<<<gV, blk, 0, stream>>>(comp, parent, minkey, mask);
    scan_kernel<<<gE, blk, 0, stream>>>(keys, comp, parent, minkey);
    select_kernel<<<gV, blk, 0, stream>>>(comp, parent, minkey, mask);
    // round 3 global + survivor compaction
    scan_append_kernel<<<gE, blk, 0, stream>>>(keys, comp, parent, minkey, eL0, cnt);
    select_kernel<<<gV, blk, 0, stream>>>(comp, parent, minkey, mask);
    // rounds 4.. in one block per batch
    finalize_kernel<<<dim3(NB), dim3(1024), 0, stream>>>(keys, comp, parent, minkey,
                                                         mask, eL0, eL1, cuL, cvL, kL, cnt);
    count_kernel<<<dim3(NCHUNK, NB), blk, 0, stream>>>(mask, counts);
    write_kernel<<<dim3(NCHUNK, NB), blk, 0, stream>>>(mask, counts, out);
}

// Round 8
// 1820.942 us; speedup vs baseline: 1.4853x; 1.4853x over previous
//
#include <hip/hip_runtime.h>
#include <hip/hip_cooperative_groups.h>
#include <cstdint>
#include <cstddef>

namespace cg = cooperative_groups;

// Problem constants (from reference: B=4, C=64, H=288, W=432, TEM=6)
#define NB 4
#define NC 64
#define HH 288
#define WW 432
#define PW 72                      // W / TEM
#define NV (HH*WW)                 // 124416 vertices
#define R_PER ((HH-1)*PW)          // 20664 row (vertical) edges per phase
#define C_PER (HH*(PW-1))          // 20448 col (horizontal) edges per phase
#define X_PER (HH*PW)              // 20736 cross edges per phase pair
#define PAIRW (R_PER + C_PER)      // 41112 weight-layout per-phase block
#define ROWS_TOT (6*R_PER)         // 123984
#define ROWCOL (6*PAIRW)           // 246672
#define NE (ROWCOL + 5*X_PER)      // 350352 edges
#define NEB ((NE + 255)/256)       // 1369 blocks per batch (init grid)
#define NEP (NEB*256)              // 350464 padded edge space (64-aligned)
#define NWORDS_P (NEP/32)          // 10952 alive-bitmask words per batch
#define NTREE (NV-1)               // 124415
#define CHUNK 4096
#define NCHUNK ((NE + CHUNK - 1)/CHUNK)   // 86
#define CBLK 512                   // coop grid: 512 blocks x 256 (2/CU, validated)

typedef unsigned long long ull;

// ---- edge id -> endpoints, per the INDEX layout (rows ++ cols ++ cross) ----
__device__ __forceinline__ void index_uv(int e, int& u, int& v) {
    if (e < ROWS_TOT) {
        int t = e / R_PER, l = e - t * R_PER;
        int h = l / PW, x = l - h * PW;
        u = h * WW + t * PW + x; v = u + WW;
    } else if (e < ROWCOL) {
        int q = e - ROWS_TOT;
        int t = q / C_PER, l = q - t * C_PER;
        int h = l / (PW-1), x = l - h * (PW-1);
        u = h * WW + t * PW + x; v = u + 1;
    } else {
        int q = e - ROWCOL;
        int t = q / X_PER, l = q - t * X_PER;
        int h = l / PW, x = l - h * PW;
        u = h * WW + t * PW + x; v = u + PW;
    }
}

// root under the per-round hook forest; handles unbroken 2-cycles (mutual min
// edge) by rooting the smaller id — the reference's (gp==idx)&(idx<parent) rule.
__device__ __forceinline__ int rootOf(const int* __restrict__ par, int c) {
    while (true) {
        int p = par[c];
        if (p == c) return c;
        int pp = par[p];
        if (pp == c) return c < p ? c : p;
        c = p;
    }
}

__global__ __launch_bounds__(256) void init_kernel(int* comp, int* parent,
                                                   ull* minkey, unsigned char* mask,
                                                   unsigned* aliveW, int* found) {
    int i = blockIdx.x * 256 + threadIdx.x;
    int b = blockIdx.y;
    if (i < NV) {
        comp[(size_t)b*NV + i] = i;
        parent[(size_t)b*NV + i] = i;
        minkey[(size_t)b*NV + i] = ~0ULL;
    }
    if (i < NE) mask[(size_t)b*NE + i] = 0;
    if (i < NWORDS_P) aliveW[(size_t)b*NWORDS_P + i] = 0xffffffffu;
    if (b == 0 && i < 2*NB) found[i] = 0;
}

// Stencil key kernel fused with Borůvka round 0 (~25 us, HBM-bound).
// Thread = vertex (h,x): 3 incident forward diffs in one channel pass; writes
// keys (weight slot == edge id) and atomicMins into minkey[u], minkey[v]
// (round-0 components are singletons).
__global__ __launch_bounds__(256) void key0_kernel(const float* __restrict__ fm,
                                                   ull* __restrict__ keys,
                                                   ull* __restrict__ minkey) {
    int i = blockIdx.x * 256 + threadIdx.x;
    int b = blockIdx.y;
    if (i >= NV) return;
    int h = i / WW, x = i - h * WW;
    int t = x / PW, xr = x - t * PW;
    bool hv = (h < HH-1);
    bool hh = (xr < PW-1);
    bool hx = (x < WW-PW);
    int ov = hv ? WW : 0;          // invalid -> reload self, diff = 0
    int oh = hh ? 1  : 0;
    int ox = hx ? PW : 0;
    const float* base = fm + (size_t)b * NC * NV + i;
    float sv = 0.f, sh_ = 0.f, sx = 0.f;
    #pragma unroll 8
    for (int ch = 0; ch < NC; ++ch) {
        const float* p = base + (size_t)ch * NV;
        float f0 = p[0];
        float dv = f0 - p[ov];
        float dh = f0 - p[oh];
        float dx = f0 - p[ox];
        sv += dv * dv; sh_ += dh * dh; sx += dx * dx;
    }
    ull* mk = minkey + (size_t)b * NV;
    ull* ky = keys + (size_t)b * NE;
    if (hv) {
        int e = t * PAIRW + h * PW + xr;
        ull k = ((ull)__float_as_uint(sv) << 32) | (unsigned int)e;
        ky[e] = k;
        int u, v; index_uv(e, u, v);
        atomicMin(&mk[u], k); atomicMin(&mk[v], k);
    }
    if (hh) {
        int e = t * PAIRW + R_PER + h * (PW-1) + xr;
        ull k = ((ull)__float_as_uint(sh_) << 32) | (unsigned int)e;
        ky[e] = k;
        int u, v; index_uv(e, u, v);
        atomicMin(&mk[u], k); atomicMin(&mk[v], k);
    }
    if (hx) {
        int e = ROWCOL + t * X_PER + h * PW + xr;
        ull k = ((ull)__float_as_uint(sx) << 32) | (unsigned int)e;
        ky[e] = k;
        int u, v; index_uv(e, u, v);
        atomicMin(&mk[u], k); atomicMin(&mk[v], k);
    }
}

// One cooperative kernel: select round 0, rounds 1..19 (scan+select, alive
// bitmask, LDS-aggregated found flags, uniform early break), then compaction.
__global__ __launch_bounds__(256)
void mst_coop_kernel(const ull* __restrict__ keys, int* __restrict__ comp,
                     int* __restrict__ parent, ull* __restrict__ minkey,
                     unsigned char* __restrict__ mask, unsigned* __restrict__ aliveW,
                     int* __restrict__ found, int* __restrict__ counts,
                     int* __restrict__ out) {
    cg::grid_group grid = cg::this_grid();
    const int tid = threadIdx.x;
    const int gtid = blockIdx.x * 256 + tid;
    const int T = gridDim.x * 256;
    const int lane = tid & 63;
    __shared__ int sFound[NB];
    __shared__ int sh[256];
    __shared__ int shOff[128];

    // ---- select round 0 (minkey prefilled by key0; comp = identity) ----
    for (int i = gtid; i < NB * NV; i += T) {
        int b = i / NV, c = i - b * NV;
        size_t off = (size_t)b * NV;
        ull k = minkey[off + c];
        if (k != ~0ULL) {
            minkey[off + c] = ~0ULL;
            int e = (int)(k & 0xffffffffu);
            mask[(size_t)b * NE + e] = 1;
            int u, v; index_uv(e, u, v);
            parent[off + c] = (u == c) ? v : u;   // comp identity at round 0
        }                                          // else parent stays c (init)
    }
    grid.sync();

    unsigned doneMask = 0;
    for (int r = 1; r < 20; ++r) {
        const int cur = r & 1, nxt = cur ^ 1;
        // ---- scan phase ----
        if (tid < NB) sFound[tid] = 0;
        if (gtid < NB) found[nxt * NB + gtid] = 0;   // slot already consumed by all
        __syncthreads();
        for (int b = 0; b < NB; ++b) {
            if (doneMask & (1u << b)) continue;
            unsigned* aw = aliveW + (size_t)b * NWORDS_P;
            const int* par = parent + (size_t)b * NV;
            int* cmp = comp + (size_t)b * NV;
            ull* mk = minkey + (size_t)b * NV;
            const ull* ky = keys + (size_t)b * NE;
            for (int e = gtid; e < NEP; e += T) {    // NEP, T both 64-aligned
                bool was = false, live = false;
                int cu = 0, cv = 0;
                if (e < NE) was = (aw[e >> 5] >> (e & 31)) & 1;
                if (was) {
                    int u, v; index_uv(e, u, v);
                    cu = rootOf(par, cmp[u]); if (cmp[u] != cu) cmp[u] = cu;
                    cv = rootOf(par, cmp[v]); if (cmp[v] != cv) cmp[v] = cv;
                    live = (cu != cv);
                }
                if (live) {
                    ull k = ky[e];
                    if (k < mk[cu]) atomicMin(&mk[cu], k);
                    if (k < mk[cv]) atomicMin(&mk[cv], k);
                }
                ull ball = __ballot(live ? 1 : 0);
                ull ballWas = __ballot(was ? 1 : 0);
                if (ball != ballWas) {               // deaths: rewrite 2 words
                    int wbase = (e - lane) >> 5;     // wave 64-aligned, in-slab
                    if (lane == 0)  aw[wbase]     = (unsigned)ball;
                    if (lane == 32) aw[wbase + 1] = (unsigned)(ball >> 32);
                }
                if (ball && lane == 0) sFound[b] = 1;  // LDS, benign race
            }
        }
        __syncthreads();
        if (tid < NB && sFound[tid]) found[cur * NB + tid] = 1;  // <=2048 stores
        grid.sync();
        int f0 = found[cur*NB+0], f1 = found[cur*NB+1],
            f2 = found[cur*NB+2], f3 = found[cur*NB+3];
        if (!f0) doneMask |= 1u;  if (!f1) doneMask |= 2u;
        if (!f2) doneMask |= 4u;  if (!f3) doneMask |= 8u;
        if (doneMask == 0xFu) break;                 // uniform across grid
        // ---- select phase (all NV: parent reset to identity is REQUIRED) ----
        for (int b = 0; b < NB; ++b) {
            int fb = (b==0)?f0:(b==1)?f1:(b==2)?f2:f3;
            if (!fb) continue;
            size_t off = (size_t)b * NV;
            for (int c = gtid; c < NV; c += T) {
                ull k = minkey[off + c];
                int par = c;
                if (k != ~0ULL) {
                    minkey[off + c] = ~0ULL;         // reset only touched slots
                    int e = (int)(k & 0xffffffffu);
                    mask[(size_t)b * NE + e] = 1;    // idempotent
                    int u, v; index_uv(e, u, v);
                    int cu = comp[off + u], cv = comp[off + v];
                    par = (cu == c) ? cv : cu;       // "other" component
                }
                if (parent[off + c] != par) parent[off + c] = par;
            }
        }
        grid.sync();
    }
    grid.sync();   // mask writes from final select visible to compaction

    // ---- compaction: per-chunk counts -> ordered write (offset from counts) ----
    for (int task = blockIdx.x; task < NB * NCHUNK; task += gridDim.x) {
        int b = task / NCHUNK, ck = task - b * NCHUNK;
        const unsigned char* m = mask + (size_t)b * NE;
        int base_e = ck * CHUNK + tid * 16;
        int cnt = 0;
        #pragma unroll
        for (int i = 0; i < 16; ++i) {
            int e = base_e + i;
            if (e < NE && m[e]) cnt++;
        }
        sh[tid] = cnt;
        __syncthreads();
        for (int o = 128; o > 0; o >>= 1) {
            if (tid < o) sh[tid] += sh[tid + o];
            __syncthreads();
        }
        if (tid == 0) counts[b * NCHUNK + ck] = sh[0];
        __syncthreads();
    }
    grid.sync();
    for (int task = blockIdx.x; task < NB * NCHUNK; task += gridDim.x) {
        int b = task / NCHUNK, ck = task - b * NCHUNK;
        shOff[tid & 127] = 0;
        __syncthreads();
        if (tid < NCHUNK && tid < ck) shOff[tid] = counts[b * NCHUNK + tid];
        __syncthreads();
        for (int o = 64; o > 0; o >>= 1) {
            if (tid < o) shOff[tid] += shOff[tid + o];
            __syncthreads();
        }
        int blockOff = shOff[0];
        const unsigned char* m = mask + (size_t)b * NE;
        int base_e = ck * CHUNK + tid * 16;
        int cnt = 0;
        #pragma unroll
        for (int i = 0; i < 16; ++i) {
            int e = base_e + i;
            if (e < NE && m[e]) cnt++;
        }
        sh[tid] = cnt;
        __syncthreads();
        for (int o = 1; o < 256; o <<= 1) {          // Hillis-Steele inclusive
            int v = 0;
            if (tid >= o) v = sh[tid - o];
            __syncthreads();
            sh[tid] += v;
            __syncthreads();
        }
        int pos = blockOff + (sh[tid] - cnt);
        for (int i = 0; i < 16; ++i) {
            int e = base_e + i;
            if (e < NE && m[e]) {
                if (pos < NTREE) out[(size_t)b * NTREE + pos] = e;
                pos++;
            }
        }
        __syncthreads();
    }
}

extern "C" void kernel_launch(void* const* d_in, const int* in_sizes, int n_in,
                              void* d_out, int out_size, void* d_ws, size_t ws_size,
                              hipStream_t stream) {
    const float* fm = (const float*)d_in[0];
    int* out = (int*)d_out;   // reference output dtype is int32

    char* ws = (char*)d_ws;
    size_t off = 0;
    auto alloc = [&](size_t bytes) -> void* {
        void* p = ws + off;
        off += (bytes + 255) & ~(size_t)255;
        return p;
    };
    ull* keys    = (ull*)alloc((size_t)NB * NE * 8);
    ull* minkey  = (ull*)alloc((size_t)NB * NV * 8);
    int* comp    = (int*)alloc((size_t)NB * NV * 4);
    int* parent  = (int*)alloc((size_t)NB * NV * 4);
    unsigned char* mask = (unsigned char*)alloc((size_t)NB * NE);
    unsigned* aliveW = (unsigned*)alloc((size_t)NB * NWORDS_P * 4);
    int* counts  = (int*)alloc((size_t)NB * NCHUNK * 4);
    int* found   = (int*)alloc(2 * NB * 4);

    dim3 blk(256);
    dim3 gE(NEB, NB);
    dim3 gV((NV + 255) / 256, NB);

    init_kernel<<<gE, blk, 0, stream>>>(comp, parent, minkey, mask, aliveW, found);
    key0_kernel<<<gV, blk, 0, stream>>>(fm, keys, minkey);   // round 0 scan fused

    void* args[] = {(void*)&keys, (void*)&comp, (void*)&parent, (void*)&minkey,
                    (void*)&mask, (void*)&aliveW, (void*)&found, (void*)&counts,
                    (void*)&out};
    hipLaunchCooperativeKernel((const void*)mst_coop_kernel,
                               dim3(CBLK), dim3(256), args, 0, stream);
}